// Round 10
// baseline (58.949 us; speedup 1.0000x reference)
//
#include <hip/hip_runtime.h>

// MoE gate fp32, B=65536 D=1024 E=8 K=2.
// R10: 32 waves/CU *and* R3's 8-fma-per-ds_read reuse.
// BLOCK=1024 (16 waves, one 64KB LDS weight copy), wave = 4 row-slots x
// 16 col-splitters, 2 rows/lane (8 rows/wave, 128 rows/block), grid=512
// -> 2 blocks/CU, 8 waves/SIMD. launch_bounds(1024,8) caps VGPR at 64,
// so no software prefetch (TLP hides latency) and lean register budget.

#define BLOCK 1024
#define DD 1024
#define EE 8
#define ROWS_PER_WAVE 8
#define ROWS_PER_BLOCK ((BLOCK / 64) * ROWS_PER_WAVE)   // 128
#define CHUNK 64                                        // 16 lanes * 4 floats
#define NCHUNK (DD / CHUNK)                             // 16

typedef float vf4 __attribute__((ext_vector_type(4)));

__global__ __launch_bounds__(BLOCK, 8) void moe_gate_kernel(
    const float* __restrict__ x,
    const float* __restrict__ gate_w,
    const float* __restrict__ gate_b,
    const float* __restrict__ expert_w,
    const float* __restrict__ expert_b,
    const int* __restrict__ kp,
    float* __restrict__ out)
{
    __shared__ float wlds[2 * EE * DD];   // 64 KiB: [gate 8x1024 | expert 8x1024]

    const int tid = threadIdx.x;

    // one-time weight preload (coalesced float4)
    {
        const float4* g4 = (const float4*)gate_w;
        const float4* e4 = (const float4*)expert_w;
        float4* w4 = (float4*)wlds;
#pragma unroll
        for (int i = 0; i < (EE * DD / 4) / BLOCK; ++i) {
            int idx = i * BLOCK + tid;
            w4[idx] = g4[idx];
            w4[EE * DD / 4 + idx] = e4[idx];
        }
    }
    __syncthreads();

    const int lane = tid & 63;
    const int wave = tid >> 6;
    const int s = lane >> 4;     // row-slot (0..3), owns rows {2s, 2s+1}
    const int j = lane & 15;     // column splitter (0..15), cols c*64 + j*4

    const int row0 = blockIdx.x * ROWS_PER_BLOCK + wave * ROWS_PER_WAVE + 2 * s;
    const float* xr0 = x + (size_t)row0 * DD + j * 4;
    const float* xr1 = xr0 + DD;

    const float* wb = wlds + j * 4;      // this lane's weight base

    float acc0[16], acc1[16];
#pragma unroll
    for (int i = 0; i < 16; ++i) { acc0[i] = 0.f; acc1[i] = 0.f; }

#pragma unroll 1
    for (int c = 0; c < NCHUNK; ++c) {
        vf4 x0 = *(const vf4*)(xr0 + c * CHUNK);
        vf4 x1 = *(const vf4*)(xr1 + c * CHUNK);
        const int wc = c * CHUNK;
#pragma unroll
        for (int o = 0; o < 16; ++o) {
            vf4 w = *(const vf4*)(wb + o * DD + wc);
            acc0[o] = fmaf(x0.x, w.x, acc0[o]);
            acc1[o] = fmaf(x1.x, w.x, acc1[o]);
            acc0[o] = fmaf(x0.y, w.y, acc0[o]);
            acc1[o] = fmaf(x1.y, w.y, acc1[o]);
            acc0[o] = fmaf(x0.z, w.z, acc0[o]);
            acc1[o] = fmaf(x1.z, w.z, acc1[o]);
            acc0[o] = fmaf(x0.w, w.w, acc0[o]);
            acc1[o] = fmaf(x1.w, w.w, acc1[o]);
        }
    }

    // reduce across the 16 column-splitter lanes (once per kernel)
#pragma unroll
    for (int i = 0; i < 16; ++i) {
        acc0[i] += __shfl_xor(acc0[i], 1);
        acc1[i] += __shfl_xor(acc1[i], 1);
        acc0[i] += __shfl_xor(acc0[i], 2);
        acc1[i] += __shfl_xor(acc1[i], 2);
        acc0[i] += __shfl_xor(acc0[i], 4);
        acc1[i] += __shfl_xor(acc1[i], 4);
        acc0[i] += __shfl_xor(acc0[i], 8);
        acc1[i] += __shfl_xor(acc1[i], 8);
    }

    if (j == 0) {
        const int k = *kp;
#pragma unroll
        for (int r = 0; r < 2; ++r) {
            const float* acc = r ? acc1 : acc0;
            float gl[8], eo[8], p[8];
#pragma unroll
            for (int e = 0; e < EE; ++e) {
                gl[e] = acc[e] + gate_b[e];
                eo[e] = acc[8 + e] + expert_b[e];
            }
            float m = gl[0];
#pragma unroll
            for (int e = 1; e < EE; ++e) m = fmaxf(m, gl[e]);
            float Z = 0.f;
#pragma unroll
            for (int e = 0; e < EE; ++e) { p[e] = __expf(gl[e] - m); Z += p[e]; }

            float res = 0.f;
            if (k >= EE) {
#pragma unroll
                for (int e = 0; e < EE; ++e) res += p[e] * eo[e];
            } else {
                float pv[8];
#pragma unroll
                for (int e = 0; e < EE; ++e) pv[e] = p[e];
                for (int t = 0; t < k; ++t) {
                    float bv = pv[0];
#pragma unroll
                    for (int e = 1; e < EE; ++e) bv = fmaxf(bv, pv[e]);
                    float sel = 0.f;
                    bool found = false;
#pragma unroll
                    for (int e = 0; e < EE; ++e) {   // first-match == lax.top_k tie rule
                        bool is = (!found) && (pv[e] == bv);
                        sel = is ? eo[e] : sel;
                        pv[e] = is ? -1.f : pv[e];
                        found = found || is;
                    }
                    res += bv * sel;
                }
            }
            out[row0 + r] = res / Z;
        }
    }
}

extern "C" void kernel_launch(void* const* d_in, const int* in_sizes, int n_in,
                              void* d_out, int out_size, void* d_ws, size_t ws_size,
                              hipStream_t stream) {
    const float* x  = (const float*)d_in[0];
    const float* gw = (const float*)d_in[1];
    const float* gb = (const float*)d_in[2];
    const float* ew = (const float*)d_in[3];
    const float* eb = (const float*)d_in[4];
    const int*   kp = (const int*)d_in[5];
    float* out = (float*)d_out;

    const int B = out_size;               // 65536
    dim3 grid(B / ROWS_PER_BLOCK), block(BLOCK);
    moe_gate_kernel<<<grid, block, 0, stream>>>(x, gw, gb, ew, eb, kp, out);
}

// Round 11
// 51.959 us; speedup vs baseline: 1.1345x; 1.1345x over previous
//
#include <hip/hip_runtime.h>

// MoE gate fp32, B=65536 D=1024 E=8 K=2.
// R11 = R3 with CHUNK 32->64 ONLY (no nt). Wave = 8 row-slots x 8 col-
// splitters, 2 rows/lane; weights in LDS (broadcast ds_read_b128, conflict-
// free). Each row-visit now reads 256B contiguous (2 consecutive vf4/lane),
// halving stream-switch rate; 4 loads in flight per lane.

#define BLOCK 512
#define DD 1024
#define EE 8
#define ROWS_PER_WAVE 16
#define ROWS_PER_BLOCK ((BLOCK / 64) * ROWS_PER_WAVE)   // 128
#define CHUNK 64
#define NCHUNK (DD / CHUNK)                             // 16

typedef float vf4 __attribute__((ext_vector_type(4)));

__global__ __launch_bounds__(BLOCK, 4) void moe_gate_kernel(
    const float* __restrict__ x,
    const float* __restrict__ gate_w,
    const float* __restrict__ gate_b,
    const float* __restrict__ expert_w,
    const float* __restrict__ expert_b,
    const int* __restrict__ kp,
    float* __restrict__ out)
{
    __shared__ float wlds[2 * EE * DD];   // 64 KiB: [gate 8x1024 | expert 8x1024]

    const int tid = threadIdx.x;

    // one-time weight preload (coalesced float4)
    {
        const float4* g4 = (const float4*)gate_w;
        const float4* e4 = (const float4*)expert_w;
        float4* w4 = (float4*)wlds;
#pragma unroll
        for (int i = 0; i < (EE * DD / 4) / BLOCK; ++i) {
            int idx = i * BLOCK + tid;
            w4[idx] = g4[idx];
            w4[EE * DD / 4 + idx] = e4[idx];
        }
    }
    __syncthreads();

    const int lane = tid & 63;
    const int wave = tid >> 6;
    const int s = lane >> 3;     // row-slot (0..7), owns rows {2s, 2s+1}
    const int j = lane & 7;      // column splitter (0..7), cols c*64 + j*8 .. +7

    const int row0 = blockIdx.x * ROWS_PER_BLOCK + wave * ROWS_PER_WAVE + 2 * s;
    const float* xr0 = x + (size_t)row0 * DD + j * 8;
    const float* xr1 = xr0 + DD;

    const float* wb = wlds + j * 8;      // this lane's weight base

    float acc0[16], acc1[16];
#pragma unroll
    for (int i = 0; i < 16; ++i) { acc0[i] = 0.f; acc1[i] = 0.f; }

    auto step = [&](int c, const vf4& x0a, const vf4& x0b,
                    const vf4& x1a, const vf4& x1b) {
        const int wc = c * CHUNK;
#pragma unroll
        for (int o = 0; o < 16; ++o) {
            vf4 wa  = *(const vf4*)(wb + o * DD + wc);
            vf4 wbv = *(const vf4*)(wb + o * DD + wc + 4);
            acc0[o] = fmaf(x0a.x, wa.x, acc0[o]);
            acc1[o] = fmaf(x1a.x, wa.x, acc1[o]);
            acc0[o] = fmaf(x0a.y, wa.y, acc0[o]);
            acc1[o] = fmaf(x1a.y, wa.y, acc1[o]);
            acc0[o] = fmaf(x0a.z, wa.z, acc0[o]);
            acc1[o] = fmaf(x1a.z, wa.z, acc1[o]);
            acc0[o] = fmaf(x0a.w, wa.w, acc0[o]);
            acc1[o] = fmaf(x1a.w, wa.w, acc1[o]);
            acc0[o] = fmaf(x0b.x, wbv.x, acc0[o]);
            acc1[o] = fmaf(x1b.x, wbv.x, acc1[o]);
            acc0[o] = fmaf(x0b.y, wbv.y, acc0[o]);
            acc1[o] = fmaf(x1b.y, wbv.y, acc1[o]);
            acc0[o] = fmaf(x0b.z, wbv.z, acc0[o]);
            acc1[o] = fmaf(x1b.z, wbv.z, acc1[o]);
            acc0[o] = fmaf(x0b.w, wbv.w, acc0[o]);
            acc1[o] = fmaf(x1b.w, wbv.w, acc1[o]);
        }
    };

    // software-pipelined: prefetch next chunk's 4 vf4 while computing current
    vf4 a0a = *(const vf4*)(xr0);
    vf4 a0b = *(const vf4*)(xr0 + 4);
    vf4 a1a = *(const vf4*)(xr1);
    vf4 a1b = *(const vf4*)(xr1 + 4);
#pragma unroll 1
    for (int c = 0; c < NCHUNK - 1; ++c) {
        const float* n0 = xr0 + (c + 1) * CHUNK;
        const float* n1 = xr1 + (c + 1) * CHUNK;
        vf4 b0a = *(const vf4*)(n0);
        vf4 b0b = *(const vf4*)(n0 + 4);
        vf4 b1a = *(const vf4*)(n1);
        vf4 b1b = *(const vf4*)(n1 + 4);
        step(c, a0a, a0b, a1a, a1b);
        a0a = b0a; a0b = b0b; a1a = b1a; a1b = b1b;
    }
    step(NCHUNK - 1, a0a, a0b, a1a, a1b);

    // reduce across the 8 column-splitter lanes (once per kernel)
#pragma unroll
    for (int i = 0; i < 16; ++i) {
        acc0[i] += __shfl_xor(acc0[i], 1);
        acc1[i] += __shfl_xor(acc1[i], 1);
        acc0[i] += __shfl_xor(acc0[i], 2);
        acc1[i] += __shfl_xor(acc1[i], 2);
        acc0[i] += __shfl_xor(acc0[i], 4);
        acc1[i] += __shfl_xor(acc1[i], 4);
    }

    if (j == 0) {
        const int k = *kp;
#pragma unroll
        for (int r = 0; r < 2; ++r) {
            const float* acc = r ? acc1 : acc0;
            float gl[8], eo[8], p[8];
#pragma unroll
            for (int e = 0; e < EE; ++e) {
                gl[e] = acc[e] + gate_b[e];
                eo[e] = acc[8 + e] + expert_b[e];
            }
            float m = gl[0];
#pragma unroll
            for (int e = 1; e < EE; ++e) m = fmaxf(m, gl[e]);
            float Z = 0.f;
#pragma unroll
            for (int e = 0; e < EE; ++e) { p[e] = __expf(gl[e] - m); Z += p[e]; }

            float res = 0.f;
            if (k >= EE) {
#pragma unroll
                for (int e = 0; e < EE; ++e) res += p[e] * eo[e];
            } else {
                float pv[8];
#pragma unroll
                for (int e = 0; e < EE; ++e) pv[e] = p[e];
                for (int t = 0; t < k; ++t) {
                    float bv = pv[0];
#pragma unroll
                    for (int e = 1; e < EE; ++e) bv = fmaxf(bv, pv[e]);
                    float sel = 0.f;
                    bool found = false;
#pragma unroll
                    for (int e = 0; e < EE; ++e) {   // first-match == lax.top_k tie rule
                        bool is = (!found) && (pv[e] == bv);
                        sel = is ? eo[e] : sel;
                        pv[e] = is ? -1.f : pv[e];
                        found = found || is;
                    }
                    res += bv * sel;
                }
            }
            out[row0 + r] = res / Z;
        }
    }
}

extern "C" void kernel_launch(void* const* d_in, const int* in_sizes, int n_in,
                              void* d_out, int out_size, void* d_ws, size_t ws_size,
                              hipStream_t stream) {
    const float* x  = (const float*)d_in[0];
    const float* gw = (const float*)d_in[1];
    const float* gb = (const float*)d_in[2];
    const float* ew = (const float*)d_in[3];
    const float* eb = (const float*)d_in[4];
    const int*   kp = (const int*)d_in[5];
    float* out = (float*)d_out;

    const int B = out_size;               // 65536
    dim3 grid(B / ROWS_PER_BLOCK), block(BLOCK);
    moe_gate_kernel<<<grid, block, 0, stream>>>(x, gw, gb, ew, eb, kp, out);
}